// Round 1
// baseline (4597.492 us; speedup 1.0000x reference)
//
#include <hip/hip_runtime.h>

#define N_NODES 100000
#define N_EDGES 1600000
#define IN_DIM 512
#define HID_DIM 128
#define OUT_DIM 64

// ---------------------------------------------------------------------------
// gemm1: support[100000,128] = X[100000,512] @ W1[512,128]   (fp32, LDS-tiled)
// Block = 256 threads, tile 64 rows x 128 cols, K-step 32.
// Thread (ty=tid/32, tx=tid%32) computes 8 rows x 4 cols micro-tile.
// ---------------------------------------------------------------------------
__global__ __launch_bounds__(256) void gemm1(const float* __restrict__ X,
                                             const float* __restrict__ W,
                                             float* __restrict__ out) {
    __shared__ float Xs[64][33];    // +1 pad breaks bank aliasing
    __shared__ float Ws[32][132];   // +4 pad keeps float4 alignment

    const int tid = threadIdx.x;
    const int tx = tid & 31;   // col group (4 cols each)
    const int ty = tid >> 5;   // row group (8 rows each)
    const int rowBase = blockIdx.x * 64;

    float acc[8][4];
#pragma unroll
    for (int i = 0; i < 8; i++)
#pragma unroll
        for (int j = 0; j < 4; j++) acc[i][j] = 0.f;

    for (int k0 = 0; k0 < IN_DIM; k0 += 32) {
        // stage Xs: 64x32 floats = 512 float4, 2 per thread
#pragma unroll
        for (int l = 0; l < 2; l++) {
            int idx = tid + l * 256;      // float4 index 0..511
            int r   = idx >> 3;           // 8 float4 per row
            int kq  = idx & 7;
            int gr  = rowBase + r;
            if (gr >= N_NODES) gr = N_NODES - 1;   // clamp (stores guarded)
            float4 v = *(const float4*)&X[(long)gr * IN_DIM + k0 + kq * 4];
            Xs[r][kq * 4 + 0] = v.x; Xs[r][kq * 4 + 1] = v.y;
            Xs[r][kq * 4 + 2] = v.z; Xs[r][kq * 4 + 3] = v.w;
        }
        // stage Ws: 32x128 floats = 1024 float4, 4 per thread
#pragma unroll
        for (int l = 0; l < 4; l++) {
            int idx = tid + l * 256;      // float4 index 0..1023
            int kr  = idx >> 5;           // 32 float4 per k-row
            int cq  = idx & 31;
            float4 v = *(const float4*)&W[(long)(k0 + kr) * HID_DIM + cq * 4];
            Ws[kr][cq * 4 + 0] = v.x; Ws[kr][cq * 4 + 1] = v.y;
            Ws[kr][cq * 4 + 2] = v.z; Ws[kr][cq * 4 + 3] = v.w;
        }
        __syncthreads();

#pragma unroll
        for (int kk = 0; kk < 32; kk++) {
            float4 bv = *(const float4*)&Ws[kk][tx * 4];   // ds_read_b128
            float b0 = bv.x, b1 = bv.y, b2 = bv.z, b3 = bv.w;
#pragma unroll
            for (int i = 0; i < 8; i++) {
                float a = Xs[ty * 8 + i][kk];              // broadcast read
                acc[i][0] += a * b0; acc[i][1] += a * b1;
                acc[i][2] += a * b2; acc[i][3] += a * b3;
            }
        }
        __syncthreads();
    }

#pragma unroll
    for (int i = 0; i < 8; i++) {
        int gr = rowBase + ty * 8 + i;
        if (gr < N_NODES) {
            float4 v = make_float4(acc[i][0], acc[i][1], acc[i][2], acc[i][3]);
            *(float4*)&out[(long)gr * HID_DIM + tx * 4] = v;
        }
    }
}

// ---------------------------------------------------------------------------
// spmm_atomic: out[row[e]] += val[e] * dense[col[e]]   (fp32 atomics)
// One thread per (edge, 4-dim chunk). D = 4 << LOGD4.
// ---------------------------------------------------------------------------
template <int LOGD4>
__global__ __launch_bounds__(256) void spmm_atomic(const int* __restrict__ rows,
                                                   const int* __restrict__ cols,
                                                   const float* __restrict__ vals,
                                                   const float* __restrict__ dense,
                                                   float* __restrict__ out) {
    const long tid = (long)blockIdx.x * blockDim.x + threadIdx.x;
    const long total = (long)N_EDGES << LOGD4;
    if (tid >= total) return;
    const int e = (int)(tid >> LOGD4);
    const int q = (int)(tid & ((1 << LOGD4) - 1));
    const int D = 4 << LOGD4;

    const int r = rows[e];
    const int c = cols[e];
    const float v = vals[e];
    float4 x = *(const float4*)&dense[(long)c * D + (q << 2)];
    float* o = out + (long)r * D + (q << 2);
    atomicAdd(o + 0, v * x.x);
    atomicAdd(o + 1, v * x.y);
    atomicAdd(o + 2, v * x.z);
    atomicAdd(o + 3, v * x.w);
}

// ---------------------------------------------------------------------------
// relu_gemm2: hw[100000,64] = relu(h[100000,128]) @ W2[128,64]
// Block = 256 threads (4 waves), W2 staged in LDS (32 KB), 4 rows per wave.
// Lane c computes output col c; h-row reads are wave-uniform (scalarized).
// ---------------------------------------------------------------------------
__global__ __launch_bounds__(256) void relu_gemm2(const float* __restrict__ h,
                                                  const float* __restrict__ W2,
                                                  float* __restrict__ out) {
    __shared__ float Ws[HID_DIM * OUT_DIM];   // 8192 floats = 32 KB
    const int tid = threadIdx.x;
#pragma unroll
    for (int l = 0; l < 8; l++) {
        int idx = (tid + l * 256) * 4;        // 2048 float4 total
        *(float4*)&Ws[idx] = *(const float4*)&W2[idx];
    }
    __syncthreads();

    const int lane = tid & 63;
    const int w = tid >> 6;
    const int rowBase = blockIdx.x * 16 + w * 4;   // 100000 = 6250 * 16 exact

#pragma unroll
    for (int i = 0; i < 4; i++) {
        const int r = rowBase + i;
        const float* hr = &h[(long)r * HID_DIM];
        float acc = 0.f;
#pragma unroll 8
        for (int k = 0; k < HID_DIM; k++) {
            float hv = hr[k];
            hv = hv > 0.f ? hv : 0.f;
            acc += hv * Ws[k * OUT_DIM + lane];   // stride-64: 2-way, free
        }
        out[(long)r * OUT_DIM + lane] = acc;
    }
}

// ---------------------------------------------------------------------------
extern "C" void kernel_launch(void* const* d_in, const int* in_sizes, int n_in,
                              void* d_out, int out_size, void* d_ws, size_t ws_size,
                              hipStream_t stream) {
    const float* feature = (const float*)d_in[0];
    const int*   erow    = (const int*)d_in[1];
    const int*   ecol    = (const int*)d_in[2];
    const float* evals   = (const float*)d_in[3];
    const float* W1      = (const float*)d_in[4];
    const float* W2      = (const float*)d_in[5];
    float* out = (float*)d_out;

    float* support = (float*)d_ws;                           // 51.2 MB
    float* h       = support + (size_t)N_NODES * HID_DIM;    // 51.2 MB
    float* hw      = support;                                // alias (support dead)

    // zero the accumulation targets (ws/out are poisoned 0xAA before each call)
    hipMemsetAsync(h,   0, (size_t)N_NODES * HID_DIM * sizeof(float), stream);
    hipMemsetAsync(out, 0, (size_t)N_NODES * OUT_DIM * sizeof(float), stream);

    // layer 1: support = X @ W1
    gemm1<<<(N_NODES + 63) / 64, 256, 0, stream>>>(feature, W1, support);

    // h = A @ support (relu applied on read in next kernel)
    {
        long total = (long)N_EDGES << 5;   // E * 128/4
        spmm_atomic<5><<<(int)((total + 255) / 256), 256, 0, stream>>>(
            erow, ecol, evals, support, h);
    }

    // hw = relu(h) @ W2   (writes alias of support — support is dead now)
    relu_gemm2<<<N_NODES / 16, 256, 0, stream>>>(h, W2, hw);

    // logits = A @ hw
    {
        long total = (long)N_EDGES << 4;   // E * 64/4
        spmm_atomic<4><<<(int)((total + 255) / 256), 256, 0, stream>>>(
            erow, ecol, evals, hw, out);
    }
}

// Round 2
// 1161.779 us; speedup vs baseline: 3.9573x; 3.9573x over previous
//
#include <hip/hip_runtime.h>

#define N_NODES 100000
#define N_EDGES 1600000
#define IN_DIM 512
#define HID_DIM 128
#define OUT_DIM 64

// ---------------------------------------------------------------------------
// gemm1: support[100000,128] = X[100000,512] @ W1[512,128]   (fp32, LDS-tiled)
// ---------------------------------------------------------------------------
__global__ __launch_bounds__(256) void gemm1(const float* __restrict__ X,
                                             const float* __restrict__ W,
                                             float* __restrict__ out) {
    __shared__ float Xs[64][33];
    __shared__ float Ws[32][132];

    const int tid = threadIdx.x;
    const int tx = tid & 31;
    const int ty = tid >> 5;
    const int rowBase = blockIdx.x * 64;

    float acc[8][4];
#pragma unroll
    for (int i = 0; i < 8; i++)
#pragma unroll
        for (int j = 0; j < 4; j++) acc[i][j] = 0.f;

    for (int k0 = 0; k0 < IN_DIM; k0 += 32) {
#pragma unroll
        for (int l = 0; l < 2; l++) {
            int idx = tid + l * 256;
            int r   = idx >> 3;
            int kq  = idx & 7;
            int gr  = rowBase + r;
            if (gr >= N_NODES) gr = N_NODES - 1;
            float4 v = *(const float4*)&X[(long)gr * IN_DIM + k0 + kq * 4];
            Xs[r][kq * 4 + 0] = v.x; Xs[r][kq * 4 + 1] = v.y;
            Xs[r][kq * 4 + 2] = v.z; Xs[r][kq * 4 + 3] = v.w;
        }
#pragma unroll
        for (int l = 0; l < 4; l++) {
            int idx = tid + l * 256;
            int kr  = idx >> 5;
            int cq  = idx & 31;
            float4 v = *(const float4*)&W[(long)(k0 + kr) * HID_DIM + cq * 4];
            Ws[kr][cq * 4 + 0] = v.x; Ws[kr][cq * 4 + 1] = v.y;
            Ws[kr][cq * 4 + 2] = v.z; Ws[kr][cq * 4 + 3] = v.w;
        }
        __syncthreads();

#pragma unroll
        for (int kk = 0; kk < 32; kk++) {
            float4 bv = *(const float4*)&Ws[kk][tx * 4];
            float b0 = bv.x, b1 = bv.y, b2 = bv.z, b3 = bv.w;
#pragma unroll
            for (int i = 0; i < 8; i++) {
                float a = Xs[ty * 8 + i][kk];
                acc[i][0] += a * b0; acc[i][1] += a * b1;
                acc[i][2] += a * b2; acc[i][3] += a * b3;
            }
        }
        __syncthreads();
    }

#pragma unroll
    for (int i = 0; i < 8; i++) {
        int gr = rowBase + ty * 8 + i;
        if (gr < N_NODES) {
            float4 v = make_float4(acc[i][0], acc[i][1], acc[i][2], acc[i][3]);
            *(float4*)&out[(long)gr * HID_DIM + tx * 4] = v;
        }
    }
}

// ---------------------------------------------------------------------------
// CSR build: histogram -> single-block exclusive scan -> scatter
// ---------------------------------------------------------------------------
__global__ __launch_bounds__(256) void hist_rows(const int* __restrict__ rows,
                                                 int* __restrict__ cnt) {
    int e = blockIdx.x * 256 + threadIdx.x;
    if (e < N_EDGES) atomicAdd(&cnt[rows[e]], 1);
}

__global__ __launch_bounds__(256) void scan_rows(const int* __restrict__ cnt,
                                                 int* __restrict__ rowptr,
                                                 int* __restrict__ cursor) {
    __shared__ int sums[256];
    const int t = threadIdx.x;
    const int CH = (N_NODES + 255) / 256;   // 391
    const int base = t * CH;
    const int lim = min(base + CH, N_NODES);
    int s = 0;
    for (int i = base; i < lim; i++) s += cnt[i];
    sums[t] = s;
    __syncthreads();
    // inclusive scan over 256 thread sums (Hillis-Steele)
    for (int off = 1; off < 256; off <<= 1) {
        int v = (t >= off) ? sums[t - off] : 0;
        __syncthreads();
        sums[t] += v;
        __syncthreads();
    }
    int run = (t == 0) ? 0 : sums[t - 1];
    for (int i = base; i < lim; i++) {
        rowptr[i] = run;
        cursor[i] = run;
        run += cnt[i];
    }
    if (t == 255) rowptr[N_NODES] = N_EDGES;
}

__global__ __launch_bounds__(256) void scatter_edges(const int* __restrict__ rows,
                                                     const int* __restrict__ cols,
                                                     const float* __restrict__ vals,
                                                     int* __restrict__ cursor,
                                                     int* __restrict__ scol,
                                                     float* __restrict__ sval) {
    int e = blockIdx.x * 256 + threadIdx.x;
    if (e < N_EDGES) {
        int p = atomicAdd(&cursor[rows[e]], 1);
        scol[p] = cols[e];
        sval[p] = vals[e];
    }
}

// ---------------------------------------------------------------------------
// spmm_csr: one wave per output row, accumulator in registers, one write.
// DPL = dims per lane (2 -> D=128 via float2, 1 -> D=64 via float).
// ---------------------------------------------------------------------------
template <int DPL>
__global__ __launch_bounds__(256) void spmm_csr(const int* __restrict__ rowptr,
                                                const int* __restrict__ scol,
                                                const float* __restrict__ sval,
                                                const float* __restrict__ dense,
                                                float* __restrict__ out) {
    const int wid = blockIdx.x * 4 + (threadIdx.x >> 6);
    if (wid >= N_NODES) return;
    const int lane = threadIdx.x & 63;
    const int start = rowptr[wid];
    const int end   = rowptr[wid + 1];

    if (DPL == 2) {
        float2 acc = make_float2(0.f, 0.f);
        int j = start;
        // 2-edge software pipeline for a little MLP
        for (; j + 1 < end; j += 2) {
            int c0 = scol[j];     float v0 = sval[j];
            int c1 = scol[j + 1]; float v1 = sval[j + 1];
            float2 x0 = *(const float2*)&dense[(long)c0 * 128 + lane * 2];
            float2 x1 = *(const float2*)&dense[(long)c1 * 128 + lane * 2];
            acc.x += v0 * x0.x; acc.y += v0 * x0.y;
            acc.x += v1 * x1.x; acc.y += v1 * x1.y;
        }
        if (j < end) {
            int c = scol[j]; float v = sval[j];
            float2 x = *(const float2*)&dense[(long)c * 128 + lane * 2];
            acc.x += v * x.x; acc.y += v * x.y;
        }
        *(float2*)&out[(long)wid * 128 + lane * 2] = acc;
    } else {
        float acc = 0.f;
        int j = start;
        for (; j + 1 < end; j += 2) {
            int c0 = scol[j];     float v0 = sval[j];
            int c1 = scol[j + 1]; float v1 = sval[j + 1];
            float x0 = dense[(long)c0 * 64 + lane];
            float x1 = dense[(long)c1 * 64 + lane];
            acc += v0 * x0 + v1 * x1;
        }
        if (j < end) {
            acc += sval[j] * dense[(long)scol[j] * 64 + lane];
        }
        out[(long)wid * 64 + lane] = acc;
    }
}

// ---------------------------------------------------------------------------
// relu_gemm2: hw[100000,64] = relu(h[100000,128]) @ W2[128,64]
// ---------------------------------------------------------------------------
__global__ __launch_bounds__(256) void relu_gemm2(const float* __restrict__ h,
                                                  const float* __restrict__ W2,
                                                  float* __restrict__ out) {
    __shared__ float Ws[HID_DIM * OUT_DIM];   // 32 KB
    const int tid = threadIdx.x;
#pragma unroll
    for (int l = 0; l < 8; l++) {
        int idx = (tid + l * 256) * 4;
        *(float4*)&Ws[idx] = *(const float4*)&W2[idx];
    }
    __syncthreads();

    const int lane = tid & 63;
    const int w = tid >> 6;
    const int rowBase = blockIdx.x * 16 + w * 4;   // 100000 = 6250 * 16

#pragma unroll
    for (int i = 0; i < 4; i++) {
        const int r = rowBase + i;
        const float* hr = &h[(long)r * HID_DIM];
        float acc = 0.f;
#pragma unroll 8
        for (int k = 0; k < HID_DIM; k++) {
            float hv = hr[k];
            hv = hv > 0.f ? hv : 0.f;
            acc += hv * Ws[k * OUT_DIM + lane];
        }
        out[(long)r * OUT_DIM + lane] = acc;
    }
}

// ---------------------------------------------------------------------------
extern "C" void kernel_launch(void* const* d_in, const int* in_sizes, int n_in,
                              void* d_out, int out_size, void* d_ws, size_t ws_size,
                              hipStream_t stream) {
    const float* feature = (const float*)d_in[0];
    const int*   erow    = (const int*)d_in[1];
    const int*   ecol    = (const int*)d_in[2];
    const float* evals   = (const float*)d_in[3];
    const float* W1      = (const float*)d_in[4];
    const float* W2      = (const float*)d_in[5];
    float* out = (float*)d_out;

    // workspace layout (~116.5 MB)
    float* support = (float*)d_ws;                           // 51.2 MB
    float* h       = support + (size_t)N_NODES * HID_DIM;    // 51.2 MB
    float* hw      = support;                                // alias (support dead)
    int*   cnt     = (int*)(h + (size_t)N_NODES * HID_DIM);  // 400 KB
    int*   cursor  = cnt + N_NODES;                          // 400 KB
    int*   rowptr  = cursor + N_NODES;                       // 400 KB
    int*   scol    = rowptr + (N_NODES + 1);                 // 6.4 MB
    float* sval    = (float*)(scol + N_EDGES);               // 6.4 MB

    // --- CSR build (counting sort by row) ---
    hipMemsetAsync(cnt, 0, (size_t)N_NODES * sizeof(int), stream);
    hist_rows<<<(N_EDGES + 255) / 256, 256, 0, stream>>>(erow, cnt);
    scan_rows<<<1, 256, 0, stream>>>(cnt, rowptr, cursor);
    scatter_edges<<<(N_EDGES + 255) / 256, 256, 0, stream>>>(erow, ecol, evals,
                                                             cursor, scol, sval);

    // layer 1: support = X @ W1
    gemm1<<<(N_NODES + 63) / 64, 256, 0, stream>>>(feature, W1, support);

    // h = A @ support  (one wave per row, no atomics, no zero-init)
    spmm_csr<2><<<(N_NODES + 3) / 4, 256, 0, stream>>>(rowptr, scol, sval,
                                                       support, h);

    // hw = relu(h) @ W2
    relu_gemm2<<<N_NODES / 16, 256, 0, stream>>>(h, W2, hw);

    // logits = A @ hw
    spmm_csr<1><<<(N_NODES + 3) / 4, 256, 0, stream>>>(rowptr, scol, sval,
                                                       hw, out);
}

// Round 3
// 940.906 us; speedup vs baseline: 4.8862x; 1.2347x over previous
//
#include <hip/hip_runtime.h>

#define N_NODES 100000
#define N_EDGES 1600000
#define IN_DIM 512
#define HID_DIM 128
#define OUT_DIM 64

// ---------------------------------------------------------------------------
// gemm1: support[100000,128] = X[100000,512] @ W1[512,128]   (fp32, LDS-tiled)
// ---------------------------------------------------------------------------
__global__ __launch_bounds__(256) void gemm1(const float* __restrict__ X,
                                             const float* __restrict__ W,
                                             float* __restrict__ out) {
    __shared__ float Xs[64][33];
    __shared__ float Ws[32][132];

    const int tid = threadIdx.x;
    const int tx = tid & 31;
    const int ty = tid >> 5;
    const int rowBase = blockIdx.x * 64;

    float acc[8][4];
#pragma unroll
    for (int i = 0; i < 8; i++)
#pragma unroll
        for (int j = 0; j < 4; j++) acc[i][j] = 0.f;

    for (int k0 = 0; k0 < IN_DIM; k0 += 32) {
#pragma unroll
        for (int l = 0; l < 2; l++) {
            int idx = tid + l * 256;
            int r   = idx >> 3;
            int kq  = idx & 7;
            int gr  = rowBase + r;
            if (gr >= N_NODES) gr = N_NODES - 1;
            float4 v = *(const float4*)&X[(long)gr * IN_DIM + k0 + kq * 4];
            Xs[r][kq * 4 + 0] = v.x; Xs[r][kq * 4 + 1] = v.y;
            Xs[r][kq * 4 + 2] = v.z; Xs[r][kq * 4 + 3] = v.w;
        }
#pragma unroll
        for (int l = 0; l < 4; l++) {
            int idx = tid + l * 256;
            int kr  = idx >> 5;
            int cq  = idx & 31;
            float4 v = *(const float4*)&W[(long)(k0 + kr) * HID_DIM + cq * 4];
            Ws[kr][cq * 4 + 0] = v.x; Ws[kr][cq * 4 + 1] = v.y;
            Ws[kr][cq * 4 + 2] = v.z; Ws[kr][cq * 4 + 3] = v.w;
        }
        __syncthreads();

#pragma unroll
        for (int kk = 0; kk < 32; kk++) {
            float4 bv = *(const float4*)&Ws[kk][tx * 4];
            float b0 = bv.x, b1 = bv.y, b2 = bv.z, b3 = bv.w;
#pragma unroll
            for (int i = 0; i < 8; i++) {
                float a = Xs[ty * 8 + i][kk];
                acc[i][0] += a * b0; acc[i][1] += a * b1;
                acc[i][2] += a * b2; acc[i][3] += a * b3;
            }
        }
        __syncthreads();
    }

#pragma unroll
    for (int i = 0; i < 8; i++) {
        int gr = rowBase + ty * 8 + i;
        if (gr < N_NODES) {
            float4 v = make_float4(acc[i][0], acc[i][1], acc[i][2], acc[i][3]);
            *(float4*)&out[(long)gr * HID_DIM + tx * 4] = v;
        }
    }
}

// ---------------------------------------------------------------------------
// CSR build: histogram -> 3-phase parallel exclusive scan -> scatter
// ---------------------------------------------------------------------------
__global__ __launch_bounds__(256) void hist_rows(const int* __restrict__ rows,
                                                 int* __restrict__ cnt) {
    int e = blockIdx.x * 256 + threadIdx.x;
    if (e < N_EDGES) atomicAdd(&cnt[rows[e]], 1);
}

#define SCAN_BLOCKS ((N_NODES + 255) / 256)   // 391

// pass1: per-256-chunk exclusive scan (in place over cnt), block totals out
__global__ __launch_bounds__(256) void scan_pass1(int* __restrict__ cnt,
                                                  int* __restrict__ bsum) {
    __shared__ int s[256];
    const int t = threadIdx.x;
    const int i = blockIdx.x * 256 + t;
    int v = (i < N_NODES) ? cnt[i] : 0;
    s[t] = v;
    __syncthreads();
    for (int off = 1; off < 256; off <<= 1) {
        int u = (t >= off) ? s[t - off] : 0;
        __syncthreads();
        s[t] += u;
        __syncthreads();
    }
    if (i < N_NODES) cnt[i] = s[t] - v;          // exclusive prefix within chunk
    if (t == 255) bsum[blockIdx.x] = s[255];     // chunk total
}

// pass2: single block scans the 391 chunk totals -> exclusive offsets
__global__ __launch_bounds__(512) void scan_pass2(int* __restrict__ bsum,
                                                  int* __restrict__ boff) {
    __shared__ int s[512];
    const int t = threadIdx.x;
    int v = (t < SCAN_BLOCKS) ? bsum[t] : 0;
    s[t] = v;
    __syncthreads();
    for (int off = 1; off < 512; off <<= 1) {
        int u = (t >= off) ? s[t - off] : 0;
        __syncthreads();
        s[t] += u;
        __syncthreads();
    }
    if (t < SCAN_BLOCKS) boff[t] = s[t] - v;     // exclusive
}

// pass3: rowptr/cursor = chunk-exclusive + chunk offset
__global__ __launch_bounds__(256) void scan_pass3(const int* __restrict__ cnt,
                                                  const int* __restrict__ boff,
                                                  int* __restrict__ rowptr,
                                                  int* __restrict__ cursor) {
    const int i = blockIdx.x * 256 + threadIdx.x;
    if (i < N_NODES) {
        int r = cnt[i] + boff[blockIdx.x];
        rowptr[i] = r;
        cursor[i] = r;
    }
    if (i == 0) rowptr[N_NODES] = N_EDGES;
}

__global__ __launch_bounds__(256) void scatter_edges(const int* __restrict__ rows,
                                                     const int* __restrict__ cols,
                                                     const float* __restrict__ vals,
                                                     int* __restrict__ cursor,
                                                     int* __restrict__ scol,
                                                     float* __restrict__ sval) {
    int e = blockIdx.x * 256 + threadIdx.x;
    if (e < N_EDGES) {
        int p = atomicAdd(&cursor[rows[e]], 1);
        scol[p] = cols[e];
        sval[p] = vals[e];
    }
}

// ---------------------------------------------------------------------------
// spmm_csr: one wave per output row, accumulator in registers, one write.
// DPL = dims per lane (2 -> D=128 via float2, 1 -> D=64 via float).
// ---------------------------------------------------------------------------
template <int DPL>
__global__ __launch_bounds__(256) void spmm_csr(const int* __restrict__ rowptr,
                                                const int* __restrict__ scol,
                                                const float* __restrict__ sval,
                                                const float* __restrict__ dense,
                                                float* __restrict__ out) {
    const int wid = blockIdx.x * 4 + (threadIdx.x >> 6);
    if (wid >= N_NODES) return;
    const int lane = threadIdx.x & 63;
    const int start = rowptr[wid];
    const int end   = rowptr[wid + 1];

    if (DPL == 2) {
        float2 acc = make_float2(0.f, 0.f);
        int j = start;
        for (; j + 1 < end; j += 2) {
            int c0 = scol[j];     float v0 = sval[j];
            int c1 = scol[j + 1]; float v1 = sval[j + 1];
            float2 x0 = *(const float2*)&dense[(long)c0 * 128 + lane * 2];
            float2 x1 = *(const float2*)&dense[(long)c1 * 128 + lane * 2];
            acc.x += v0 * x0.x; acc.y += v0 * x0.y;
            acc.x += v1 * x1.x; acc.y += v1 * x1.y;
        }
        if (j < end) {
            int c = scol[j]; float v = sval[j];
            float2 x = *(const float2*)&dense[(long)c * 128 + lane * 2];
            acc.x += v * x.x; acc.y += v * x.y;
        }
        *(float2*)&out[(long)wid * 128 + lane * 2] = acc;
    } else {
        float acc = 0.f;
        int j = start;
        for (; j + 1 < end; j += 2) {
            int c0 = scol[j];     float v0 = sval[j];
            int c1 = scol[j + 1]; float v1 = sval[j + 1];
            float x0 = dense[(long)c0 * 64 + lane];
            float x1 = dense[(long)c1 * 64 + lane];
            acc += v0 * x0 + v1 * x1;
        }
        if (j < end) {
            acc += sval[j] * dense[(long)scol[j] * 64 + lane];
        }
        out[(long)wid * 64 + lane] = acc;
    }
}

// ---------------------------------------------------------------------------
// relu_gemm2: hw[100000,64] = relu(h[100000,128]) @ W2[128,64]
// ---------------------------------------------------------------------------
__global__ __launch_bounds__(256) void relu_gemm2(const float* __restrict__ h,
                                                  const float* __restrict__ W2,
                                                  float* __restrict__ out) {
    __shared__ float Ws[HID_DIM * OUT_DIM];   // 32 KB
    const int tid = threadIdx.x;
#pragma unroll
    for (int l = 0; l < 8; l++) {
        int idx = (tid + l * 256) * 4;
        *(float4*)&Ws[idx] = *(const float4*)&W2[idx];
    }
    __syncthreads();

    const int lane = tid & 63;
    const int w = tid >> 6;
    const int rowBase = blockIdx.x * 16 + w * 4;   // 100000 = 6250 * 16

#pragma unroll
    for (int i = 0; i < 4; i++) {
        const int r = rowBase + i;
        const float* hr = &h[(long)r * HID_DIM];
        float acc = 0.f;
#pragma unroll 8
        for (int k = 0; k < HID_DIM; k++) {
            float hv = hr[k];
            hv = hv > 0.f ? hv : 0.f;
            acc += hv * Ws[k * OUT_DIM + lane];
        }
        out[(long)r * OUT_DIM + lane] = acc;
    }
}

// ---------------------------------------------------------------------------
extern "C" void kernel_launch(void* const* d_in, const int* in_sizes, int n_in,
                              void* d_out, int out_size, void* d_ws, size_t ws_size,
                              hipStream_t stream) {
    const float* feature = (const float*)d_in[0];
    const int*   erow    = (const int*)d_in[1];
    const int*   ecol    = (const int*)d_in[2];
    const float* evals   = (const float*)d_in[3];
    const float* W1      = (const float*)d_in[4];
    const float* W2      = (const float*)d_in[5];
    float* out = (float*)d_out;

    // workspace layout (~117 MB)
    float* support = (float*)d_ws;                           // 51.2 MB
    float* h       = support + (size_t)N_NODES * HID_DIM;    // 51.2 MB
    float* hw      = support;                                // alias (support dead)
    int*   cnt     = (int*)(h + (size_t)N_NODES * HID_DIM);  // 400 KB
    int*   cursor  = cnt + N_NODES;                          // 400 KB
    int*   rowptr  = cursor + N_NODES;                       // 400 KB
    int*   scol    = rowptr + (N_NODES + 1);                 // 6.4 MB
    float* sval    = (float*)(scol + N_EDGES);               // 6.4 MB
    int*   bsum    = (int*)(sval + N_EDGES);                 // 1.6 KB
    int*   boff    = bsum + SCAN_BLOCKS;                     // 1.6 KB

    // --- CSR build (counting sort by row) ---
    hipMemsetAsync(cnt, 0, (size_t)N_NODES * sizeof(int), stream);
    hist_rows<<<(N_EDGES + 255) / 256, 256, 0, stream>>>(erow, cnt);
    scan_pass1<<<SCAN_BLOCKS, 256, 0, stream>>>(cnt, bsum);
    scan_pass2<<<1, 512, 0, stream>>>(bsum, boff);
    scan_pass3<<<SCAN_BLOCKS, 256, 0, stream>>>(cnt, boff, rowptr, cursor);
    scatter_edges<<<(N_EDGES + 255) / 256, 256, 0, stream>>>(erow, ecol, evals,
                                                             cursor, scol, sval);

    // layer 1: support = X @ W1
    gemm1<<<(N_NODES + 63) / 64, 256, 0, stream>>>(feature, W1, support);

    // h = A @ support  (one wave per row, no atomics, no zero-init)
    spmm_csr<2><<<(N_NODES + 3) / 4, 256, 0, stream>>>(rowptr, scol, sval,
                                                       support, h);

    // hw = relu(h) @ W2
    relu_gemm2<<<N_NODES / 16, 256, 0, stream>>>(h, W2, hw);

    // logits = A @ hw
    spmm_csr<1><<<(N_NODES + 3) / 4, 256, 0, stream>>>(rowptr, scol, sval,
                                                       hw, out);
}

// Round 4
// 852.327 us; speedup vs baseline: 5.3941x; 1.1039x over previous
//
#include <hip/hip_runtime.h>

#define N_NODES 100000
#define N_EDGES 1600000
#define IN_DIM 512
#define HID_DIM 128
#define OUT_DIM 64

typedef __attribute__((ext_vector_type(8))) short bf16x8;
typedef __attribute__((ext_vector_type(4))) float f32x4;

__device__ __forceinline__ unsigned int f2bf_rne(float f) {
    union { float f; unsigned u; } v; v.f = f;
    unsigned r = v.u + 0x7fffu + ((v.u >> 16) & 1u);   // round-to-nearest-even
    return r >> 16;
}

// ---------------------------------------------------------------------------
// wcvt: W1t[128][512] bf16 = transpose(W1[512][128] fp32)   (one-shot, 16 blk)
// ---------------------------------------------------------------------------
__global__ __launch_bounds__(256) void wcvt(const float* __restrict__ W1,
                                            unsigned short* __restrict__ W1t) {
    __shared__ float T[64][65];
    const int bk = blockIdx.x >> 1;      // 8 k-tiles
    const int bn = blockIdx.x & 1;       // 2 n-tiles
    const int t = threadIdx.x;
    // read 64k x 64n fp32, coalesced
#pragma unroll
    for (int i = 0; i < 4; i++) {
        int fi = t + i * 256;            // float4 idx 0..1023
        int kk = fi >> 4;
        int f  = fi & 15;
        float4 v = *(const float4*)&W1[(long)(bk * 64 + kk) * HID_DIM + bn * 64 + f * 4];
        T[kk][f * 4 + 0] = v.x; T[kk][f * 4 + 1] = v.y;
        T[kk][f * 4 + 2] = v.z; T[kk][f * 4 + 3] = v.w;
    }
    __syncthreads();
    // write W1t[n][k] bf16, coalesced (dword = 2 bf16)
#pragma unroll
    for (int i = 0; i < 8; i++) {
        int di = t + i * 256;            // dword idx 0..2047
        int n  = di >> 5;
        int dw = di & 31;
        unsigned lo = f2bf_rne(T[dw * 2 + 0][n]);
        unsigned hi = f2bf_rne(T[dw * 2 + 1][n]);
        unsigned short* dst = W1t + (long)(bn * 64 + n) * IN_DIM + bk * 64 + dw * 2;
        *(unsigned int*)dst = lo | (hi << 16);
    }
}

// ---------------------------------------------------------------------------
// gemm1_mfma: support[100000,128] = X[100000,512] @ W1   (bf16 MFMA, fp32 acc)
// Block: 64 rows x 128 cols, 4 waves, wave = 32-col strip.
// A staged in LDS (bf16, pad 40), B frags loaded direct from W1t (L2-hot).
// ---------------------------------------------------------------------------
__global__ __launch_bounds__(256) void gemm1_mfma(const float* __restrict__ X,
                                                  const unsigned short* __restrict__ W1t,
                                                  float* __restrict__ out) {
    __shared__ unsigned short As[64][40];   // 5 KB, +8 pad: frag reads 2-way = free
    const int tid  = threadIdx.x;
    const int lane = tid & 63;
    const int w    = tid >> 6;
    const int m    = lane & 15;
    const int hi   = lane >> 4;
    const int rowBase = blockIdx.x * 64;

    f32x4 acc[4][2] = {};

    // A staging: thread -> (row sr, k-offset sk), 8 floats per k-step
    const int sr = tid >> 2;
    const int sk = (tid & 3) * 8;
    int gr = rowBase + sr;
    if (gr >= N_NODES) gr = N_NODES - 1;    // clamped read; stores guarded
    const float* xp = X + (long)gr * IN_DIM;

    // B fragment base pointers (k-contiguous rows of W1t)
    const unsigned short* b0p = W1t + (long)(w * 32 + m) * IN_DIM + hi * 8;
    const unsigned short* b1p = W1t + (long)(w * 32 + 16 + m) * IN_DIM + hi * 8;

    for (int k0 = 0; k0 < IN_DIM; k0 += 32) {
        float4 xa = *(const float4*)(xp + k0 + sk);
        float4 xb = *(const float4*)(xp + k0 + sk + 4);
        uint4 pk;
        pk.x = f2bf_rne(xa.x) | (f2bf_rne(xa.y) << 16);
        pk.y = f2bf_rne(xa.z) | (f2bf_rne(xa.w) << 16);
        pk.z = f2bf_rne(xb.x) | (f2bf_rne(xb.y) << 16);
        pk.w = f2bf_rne(xb.z) | (f2bf_rne(xb.w) << 16);
        *(uint4*)&As[sr][sk] = pk;          // ds_write_b128, 16B aligned
        __syncthreads();

        bf16x8 bf0 = *(const bf16x8*)(b0p + k0);   // global dwordx4, L2-hot
        bf16x8 bf1 = *(const bf16x8*)(b1p + k0);
#pragma unroll
        for (int t = 0; t < 4; t++) {
            bf16x8 af = *(const bf16x8*)&As[t * 16 + m][hi * 8];
            acc[t][0] = __builtin_amdgcn_mfma_f32_16x16x32_bf16(af, bf0, acc[t][0], 0, 0, 0);
            acc[t][1] = __builtin_amdgcn_mfma_f32_16x16x32_bf16(af, bf1, acc[t][1], 0, 0, 0);
        }
        __syncthreads();
    }

    // D layout (m89-verified): col = lane&15, row = (lane>>4)*4 + reg
#pragma unroll
    for (int t = 0; t < 4; t++) {
#pragma unroll
        for (int r = 0; r < 4; r++) {
            int row = rowBase + t * 16 + hi * 4 + r;
            if (row < N_NODES) {
                out[(long)row * HID_DIM + w * 32 + m]      = acc[t][0][r];
                out[(long)row * HID_DIM + w * 32 + 16 + m] = acc[t][1][r];
            }
        }
    }
}

// ---------------------------------------------------------------------------
// CSR build: histogram -> 3-phase parallel exclusive scan -> scatter
// ---------------------------------------------------------------------------
__global__ __launch_bounds__(256) void hist_rows(const int* __restrict__ rows,
                                                 int* __restrict__ cnt) {
    int e = blockIdx.x * 256 + threadIdx.x;
    if (e < N_EDGES) atomicAdd(&cnt[rows[e]], 1);
}

#define SCAN_BLOCKS ((N_NODES + 255) / 256)   // 391

__global__ __launch_bounds__(256) void scan_pass1(int* __restrict__ cnt,
                                                  int* __restrict__ bsum) {
    __shared__ int s[256];
    const int t = threadIdx.x;
    const int i = blockIdx.x * 256 + t;
    int v = (i < N_NODES) ? cnt[i] : 0;
    s[t] = v;
    __syncthreads();
    for (int off = 1; off < 256; off <<= 1) {
        int u = (t >= off) ? s[t - off] : 0;
        __syncthreads();
        s[t] += u;
        __syncthreads();
    }
    if (i < N_NODES) cnt[i] = s[t] - v;
    if (t == 255) bsum[blockIdx.x] = s[255];
}

__global__ __launch_bounds__(512) void scan_pass2(int* __restrict__ bsum,
                                                  int* __restrict__ boff) {
    __shared__ int s[512];
    const int t = threadIdx.x;
    int v = (t < SCAN_BLOCKS) ? bsum[t] : 0;
    s[t] = v;
    __syncthreads();
    for (int off = 1; off < 512; off <<= 1) {
        int u = (t >= off) ? s[t - off] : 0;
        __syncthreads();
        s[t] += u;
        __syncthreads();
    }
    if (t < SCAN_BLOCKS) boff[t] = s[t] - v;
}

__global__ __launch_bounds__(256) void scan_pass3(const int* __restrict__ cnt,
                                                  const int* __restrict__ boff,
                                                  int* __restrict__ rowptr,
                                                  int* __restrict__ cursor) {
    const int i = blockIdx.x * 256 + threadIdx.x;
    if (i < N_NODES) {
        int r = cnt[i] + boff[blockIdx.x];
        rowptr[i] = r;
        cursor[i] = r;
    }
    if (i == 0) rowptr[N_NODES] = N_EDGES;
}

__global__ __launch_bounds__(256) void scatter_edges(const int* __restrict__ rows,
                                                     const int* __restrict__ cols,
                                                     const float* __restrict__ vals,
                                                     int* __restrict__ cursor,
                                                     int* __restrict__ scol,
                                                     float* __restrict__ sval) {
    int e = blockIdx.x * 256 + threadIdx.x;
    if (e < N_EDGES) {
        int p = atomicAdd(&cursor[rows[e]], 1);
        scol[p] = cols[e];
        sval[p] = vals[e];
    }
}

// ---------------------------------------------------------------------------
// spmm_csr: one wave per output row, accumulator in registers, one write.
// ---------------------------------------------------------------------------
template <int DPL>
__global__ __launch_bounds__(256) void spmm_csr(const int* __restrict__ rowptr,
                                                const int* __restrict__ scol,
                                                const float* __restrict__ sval,
                                                const float* __restrict__ dense,
                                                float* __restrict__ out) {
    const int wid = blockIdx.x * 4 + (threadIdx.x >> 6);
    if (wid >= N_NODES) return;
    const int lane = threadIdx.x & 63;
    const int start = rowptr[wid];
    const int end   = rowptr[wid + 1];

    if (DPL == 2) {
        float2 acc = make_float2(0.f, 0.f);
        int j = start;
        for (; j + 1 < end; j += 2) {
            int c0 = scol[j];     float v0 = sval[j];
            int c1 = scol[j + 1]; float v1 = sval[j + 1];
            float2 x0 = *(const float2*)&dense[(long)c0 * 128 + lane * 2];
            float2 x1 = *(const float2*)&dense[(long)c1 * 128 + lane * 2];
            acc.x += v0 * x0.x; acc.y += v0 * x0.y;
            acc.x += v1 * x1.x; acc.y += v1 * x1.y;
        }
        if (j < end) {
            int c = scol[j]; float v = sval[j];
            float2 x = *(const float2*)&dense[(long)c * 128 + lane * 2];
            acc.x += v * x.x; acc.y += v * x.y;
        }
        *(float2*)&out[(long)wid * 128 + lane * 2] = acc;
    } else {
        float acc = 0.f;
        int j = start;
        for (; j + 1 < end; j += 2) {
            int c0 = scol[j];     float v0 = sval[j];
            int c1 = scol[j + 1]; float v1 = sval[j + 1];
            float x0 = dense[(long)c0 * 64 + lane];
            float x1 = dense[(long)c1 * 64 + lane];
            acc += v0 * x0 + v1 * x1;
        }
        if (j < end) {
            acc += sval[j] * dense[(long)scol[j] * 64 + lane];
        }
        out[(long)wid * 64 + lane] = acc;
    }
}

// ---------------------------------------------------------------------------
// relu_gemm2: hw[100000,64] = relu(h[100000,128]) @ W2[128,64]
// ---------------------------------------------------------------------------
__global__ __launch_bounds__(256) void relu_gemm2(const float* __restrict__ h,
                                                  const float* __restrict__ W2,
                                                  float* __restrict__ out) {
    __shared__ float Ws[HID_DIM * OUT_DIM];   // 32 KB
    const int tid = threadIdx.x;
#pragma unroll
    for (int l = 0; l < 8; l++) {
        int idx = (tid + l * 256) * 4;
        *(float4*)&Ws[idx] = *(const float4*)&W2[idx];
    }
    __syncthreads();

    const int lane = tid & 63;
    const int w = tid >> 6;
    const int rowBase = blockIdx.x * 16 + w * 4;   // 100000 = 6250 * 16

#pragma unroll
    for (int i = 0; i < 4; i++) {
        const int r = rowBase + i;
        const float* hr = &h[(long)r * HID_DIM];
        float acc = 0.f;
#pragma unroll 8
        for (int k = 0; k < HID_DIM; k++) {
            float hv = hr[k];
            hv = hv > 0.f ? hv : 0.f;
            acc += hv * Ws[k * OUT_DIM + lane];
        }
        out[(long)r * OUT_DIM + lane] = acc;
    }
}

// ---------------------------------------------------------------------------
extern "C" void kernel_launch(void* const* d_in, const int* in_sizes, int n_in,
                              void* d_out, int out_size, void* d_ws, size_t ws_size,
                              hipStream_t stream) {
    const float* feature = (const float*)d_in[0];
    const int*   erow    = (const int*)d_in[1];
    const int*   ecol    = (const int*)d_in[2];
    const float* evals   = (const float*)d_in[3];
    const float* W1      = (const float*)d_in[4];
    const float* W2      = (const float*)d_in[5];
    float* out = (float*)d_out;

    // workspace layout (~118 MB)
    float* support = (float*)d_ws;                           // 51.2 MB
    float* h       = support + (size_t)N_NODES * HID_DIM;    // 51.2 MB
    float* hw      = support;                                // alias (support dead)
    int*   cnt     = (int*)(h + (size_t)N_NODES * HID_DIM);  // 400 KB
    int*   cursor  = cnt + N_NODES;                          // 400 KB
    int*   rowptr  = cursor + N_NODES;                       // 400 KB
    int*   scol    = rowptr + (N_NODES + 1);                 // 6.4 MB
    float* sval    = (float*)(scol + N_EDGES);               // 6.4 MB
    int*   bsum    = (int*)(sval + N_EDGES);                 // 1.6 KB
    int*   boff    = bsum + SCAN_BLOCKS;                     // 1.6 KB
    unsigned short* W1t = (unsigned short*)(boff + SCAN_BLOCKS); // 128 KB bf16

    // --- CSR build (counting sort by row) ---
    hipMemsetAsync(cnt, 0, (size_t)N_NODES * sizeof(int), stream);
    hist_rows<<<(N_EDGES + 255) / 256, 256, 0, stream>>>(erow, cnt);
    scan_pass1<<<SCAN_BLOCKS, 256, 0, stream>>>(cnt, bsum);
    scan_pass2<<<1, 512, 0, stream>>>(bsum, boff);
    scan_pass3<<<SCAN_BLOCKS, 256, 0, stream>>>(cnt, boff, rowptr, cursor);
    scatter_edges<<<(N_EDGES + 255) / 256, 256, 0, stream>>>(erow, ecol, evals,
                                                             cursor, scol, sval);

    // --- W1 transpose+convert, then layer 1 GEMM on MFMA ---
    wcvt<<<16, 256, 0, stream>>>(W1, W1t);
    gemm1_mfma<<<(N_NODES + 63) / 64, 256, 0, stream>>>(feature, W1t, support);

    // h = A @ support
    spmm_csr<2><<<(N_NODES + 3) / 4, 256, 0, stream>>>(rowptr, scol, sval,
                                                       support, h);

    // hw = relu(h) @ W2
    relu_gemm2<<<N_NODES / 16, 256, 0, stream>>>(h, W2, hw);

    // logits = A @ hw
    spmm_csr<1><<<(N_NODES + 3) / 4, 256, 0, stream>>>(rowptr, scol, sval,
                                                       hw, out);
}

// Round 5
// 728.893 us; speedup vs baseline: 6.3075x; 1.1693x over previous
//
#include <hip/hip_runtime.h>

#define N_NODES 100000
#define N_EDGES 1600000
#define IN_DIM 512
#define HID_DIM 128
#define OUT_DIM 64

typedef __attribute__((ext_vector_type(8))) short bf16x8;
typedef __attribute__((ext_vector_type(4))) float f32x4;

__device__ __forceinline__ unsigned int f2bf_rne(float f) {
    union { float f; unsigned u; } v; v.f = f;
    unsigned r = v.u + 0x7fffu + ((v.u >> 16) & 1u);   // round-to-nearest-even
    return r >> 16;
}

// ---------------------------------------------------------------------------
// wcvt: W1t[128][512] bf16 = transpose(W1[512][128] fp32)   (one-shot, 16 blk)
// ---------------------------------------------------------------------------
__global__ __launch_bounds__(256) void wcvt(const float* __restrict__ W1,
                                            unsigned short* __restrict__ W1t) {
    __shared__ float T[64][65];
    const int bk = blockIdx.x >> 1;      // 8 k-tiles
    const int bn = blockIdx.x & 1;       // 2 n-tiles
    const int t = threadIdx.x;
#pragma unroll
    for (int i = 0; i < 4; i++) {
        int fi = t + i * 256;
        int kk = fi >> 4;
        int f  = fi & 15;
        float4 v = *(const float4*)&W1[(long)(bk * 64 + kk) * HID_DIM + bn * 64 + f * 4];
        T[kk][f * 4 + 0] = v.x; T[kk][f * 4 + 1] = v.y;
        T[kk][f * 4 + 2] = v.z; T[kk][f * 4 + 3] = v.w;
    }
    __syncthreads();
#pragma unroll
    for (int i = 0; i < 8; i++) {
        int di = t + i * 256;
        int n  = di >> 5;
        int dw = di & 31;
        unsigned lo = f2bf_rne(T[dw * 2 + 0][n]);
        unsigned hi = f2bf_rne(T[dw * 2 + 1][n]);
        unsigned short* dst = W1t + (long)(bn * 64 + n) * IN_DIM + bk * 64 + dw * 2;
        *(unsigned int*)dst = lo | (hi << 16);
    }
}

// ---------------------------------------------------------------------------
// wcvt2: W2t[64][128] bf16 = transpose(W2[128][64] fp32)   (one-shot, 1 blk)
// ---------------------------------------------------------------------------
__global__ __launch_bounds__(256) void wcvt2(const float* __restrict__ W2,
                                             unsigned short* __restrict__ W2t) {
    __shared__ float T[128][65];
    const int t = threadIdx.x;
#pragma unroll
    for (int i = 0; i < 8; i++) {
        int fi = t + i * 256;            // float4 idx 0..2047
        int k = fi >> 4;
        int f = fi & 15;
        float4 v = *(const float4*)&W2[(long)k * OUT_DIM + f * 4];
        T[k][f * 4 + 0] = v.x; T[k][f * 4 + 1] = v.y;
        T[k][f * 4 + 2] = v.z; T[k][f * 4 + 3] = v.w;
    }
    __syncthreads();
#pragma unroll
    for (int i = 0; i < 16; i++) {
        int di = t + i * 256;            // dword idx 0..4095
        int n  = di >> 6;
        int dw = di & 63;
        unsigned lo = f2bf_rne(T[dw * 2 + 0][n]);
        unsigned hi = f2bf_rne(T[dw * 2 + 1][n]);
        *(unsigned int*)(W2t + (long)n * HID_DIM + dw * 2) = lo | (hi << 16);
    }
}

// ---------------------------------------------------------------------------
// gemm1_mfma: support[100000,128] = X[100000,512] @ W1   (bf16 MFMA, fp32 acc)
// ---------------------------------------------------------------------------
__global__ __launch_bounds__(256) void gemm1_mfma(const float* __restrict__ X,
                                                  const unsigned short* __restrict__ W1t,
                                                  float* __restrict__ out) {
    __shared__ unsigned short As[64][40];
    const int tid  = threadIdx.x;
    const int lane = tid & 63;
    const int w    = tid >> 6;
    const int m    = lane & 15;
    const int hi   = lane >> 4;
    const int rowBase = blockIdx.x * 64;

    f32x4 acc[4][2] = {};

    const int sr = tid >> 2;
    const int sk = (tid & 3) * 8;
    int gr = rowBase + sr;
    if (gr >= N_NODES) gr = N_NODES - 1;
    const float* xp = X + (long)gr * IN_DIM;

    const unsigned short* b0p = W1t + (long)(w * 32 + m) * IN_DIM + hi * 8;
    const unsigned short* b1p = W1t + (long)(w * 32 + 16 + m) * IN_DIM + hi * 8;

    for (int k0 = 0; k0 < IN_DIM; k0 += 32) {
        float4 xa = *(const float4*)(xp + k0 + sk);
        float4 xb = *(const float4*)(xp + k0 + sk + 4);
        uint4 pk;
        pk.x = f2bf_rne(xa.x) | (f2bf_rne(xa.y) << 16);
        pk.y = f2bf_rne(xa.z) | (f2bf_rne(xa.w) << 16);
        pk.z = f2bf_rne(xb.x) | (f2bf_rne(xb.y) << 16);
        pk.w = f2bf_rne(xb.z) | (f2bf_rne(xb.w) << 16);
        *(uint4*)&As[sr][sk] = pk;
        __syncthreads();

        bf16x8 bf0 = *(const bf16x8*)(b0p + k0);
        bf16x8 bf1 = *(const bf16x8*)(b1p + k0);
#pragma unroll
        for (int t = 0; t < 4; t++) {
            bf16x8 af = *(const bf16x8*)&As[t * 16 + m][hi * 8];
            acc[t][0] = __builtin_amdgcn_mfma_f32_16x16x32_bf16(af, bf0, acc[t][0], 0, 0, 0);
            acc[t][1] = __builtin_amdgcn_mfma_f32_16x16x32_bf16(af, bf1, acc[t][1], 0, 0, 0);
        }
        __syncthreads();
    }

#pragma unroll
    for (int t = 0; t < 4; t++) {
#pragma unroll
        for (int r = 0; r < 4; r++) {
            int row = rowBase + t * 16 + hi * 4 + r;
            if (row < N_NODES) {
                out[(long)row * HID_DIM + w * 32 + m]      = acc[t][0][r];
                out[(long)row * HID_DIM + w * 32 + 16 + m] = acc[t][1][r];
            }
        }
    }
}

// ---------------------------------------------------------------------------
// gemm2_mfma: hw[100000,64] = h_bf16[100000,128] @ W2   (W2 register-resident)
// Block: 128 rows x 64 cols, 4 waves x 32 rows. No LDS, no barriers.
// ---------------------------------------------------------------------------
__global__ __launch_bounds__(256) void gemm2_mfma(const unsigned short* __restrict__ hb,
                                                  const unsigned short* __restrict__ W2t,
                                                  float* __restrict__ hw) {
    const int tid  = threadIdx.x;
    const int lane = tid & 63;
    const int w    = tid >> 6;
    const int m    = lane & 15;
    const int hi   = lane >> 4;
    const long rowBase = (long)blockIdx.x * 128 + w * 32;

    // register-resident B fragments (entire W2: 16 x bf16x8 = 64 VGPRs)
    bf16x8 bfrag[4][4];   // [kstep][ntile]
#pragma unroll
    for (int nt = 0; nt < 4; nt++) {
        const unsigned short* bp = W2t + (long)(nt * 16 + m) * HID_DIM + hi * 8;
#pragma unroll
        for (int ks = 0; ks < 4; ks++)
            bfrag[ks][nt] = *(const bf16x8*)(bp + ks * 32);
    }

    f32x4 acc[2][4] = {};
#pragma unroll
    for (int mt = 0; mt < 2; mt++) {
        long r = rowBase + mt * 16 + m;
        if (r >= N_NODES) r = N_NODES - 1;       // clamped load; stores guarded
        const unsigned short* ap = hb + r * HID_DIM + hi * 8;
#pragma unroll
        for (int ks = 0; ks < 4; ks++) {
            bf16x8 af = *(const bf16x8*)(ap + ks * 32);
#pragma unroll
            for (int nt = 0; nt < 4; nt++)
                acc[mt][nt] = __builtin_amdgcn_mfma_f32_16x16x32_bf16(
                    af, bfrag[ks][nt], acc[mt][nt], 0, 0, 0);
        }
    }

#pragma unroll
    for (int mt = 0; mt < 2; mt++)
#pragma unroll
        for (int nt = 0; nt < 4; nt++)
#pragma unroll
            for (int r = 0; r < 4; r++) {
                long row = rowBase + mt * 16 + hi * 4 + r;
                if (row < N_NODES)
                    hw[row * OUT_DIM + nt * 16 + m] = acc[mt][nt][r];
            }
}

// ---------------------------------------------------------------------------
// CSR build: histogram -> 3-phase parallel exclusive scan -> scatter
// ---------------------------------------------------------------------------
__global__ __launch_bounds__(256) void hist_rows(const int* __restrict__ rows,
                                                 int* __restrict__ cnt) {
    int e = blockIdx.x * 256 + threadIdx.x;
    if (e < N_EDGES) atomicAdd(&cnt[rows[e]], 1);
}

#define SCAN_BLOCKS ((N_NODES + 255) / 256)   // 391

__global__ __launch_bounds__(256) void scan_pass1(int* __restrict__ cnt,
                                                  int* __restrict__ bsum) {
    __shared__ int s[256];
    const int t = threadIdx.x;
    const int i = blockIdx.x * 256 + t;
    int v = (i < N_NODES) ? cnt[i] : 0;
    s[t] = v;
    __syncthreads();
    for (int off = 1; off < 256; off <<= 1) {
        int u = (t >= off) ? s[t - off] : 0;
        __syncthreads();
        s[t] += u;
        __syncthreads();
    }
    if (i < N_NODES) cnt[i] = s[t] - v;
    if (t == 255) bsum[blockIdx.x] = s[255];
}

__global__ __launch_bounds__(512) void scan_pass2(int* __restrict__ bsum,
                                                  int* __restrict__ boff) {
    __shared__ int s[512];
    const int t = threadIdx.x;
    int v = (t < SCAN_BLOCKS) ? bsum[t] : 0;
    s[t] = v;
    __syncthreads();
    for (int off = 1; off < 512; off <<= 1) {
        int u = (t >= off) ? s[t - off] : 0;
        __syncthreads();
        s[t] += u;
        __syncthreads();
    }
    if (t < SCAN_BLOCKS) boff[t] = s[t] - v;
}

__global__ __launch_bounds__(256) void scan_pass3(const int* __restrict__ cnt,
                                                  const int* __restrict__ boff,
                                                  int* __restrict__ rowptr,
                                                  int* __restrict__ cursor) {
    const int i = blockIdx.x * 256 + threadIdx.x;
    if (i < N_NODES) {
        int r = cnt[i] + boff[blockIdx.x];
        rowptr[i] = r;
        cursor[i] = r;
    }
    if (i == 0) rowptr[N_NODES] = N_EDGES;
}

__global__ __launch_bounds__(256) void scatter_edges(const int* __restrict__ rows,
                                                     const int* __restrict__ cols,
                                                     const float* __restrict__ vals,
                                                     int* __restrict__ cursor,
                                                     int* __restrict__ scol,
                                                     float* __restrict__ sval) {
    int e = blockIdx.x * 256 + threadIdx.x;
    if (e < N_EDGES) {
        int p = atomicAdd(&cursor[rows[e]], 1);
        scol[p] = cols[e];
        sval[p] = vals[e];
    }
}

// ---------------------------------------------------------------------------
// spmm1: h_bf16[row] = relu(sum v * support[col]) ; one wave per row, D=128
// ---------------------------------------------------------------------------
__global__ __launch_bounds__(256) void spmm1(const int* __restrict__ rowptr,
                                             const int* __restrict__ scol,
                                             const float* __restrict__ sval,
                                             const float* __restrict__ dense,
                                             unsigned short* __restrict__ outb) {
    const int wid = blockIdx.x * 4 + (threadIdx.x >> 6);
    if (wid >= N_NODES) return;
    const int lane = threadIdx.x & 63;
    const int start = rowptr[wid];
    const int end   = rowptr[wid + 1];

    float2 acc = make_float2(0.f, 0.f);
    int j = start;
    for (; j + 1 < end; j += 2) {
        int c0 = scol[j];     float v0 = sval[j];
        int c1 = scol[j + 1]; float v1 = sval[j + 1];
        float2 x0 = *(const float2*)&dense[(long)c0 * 128 + lane * 2];
        float2 x1 = *(const float2*)&dense[(long)c1 * 128 + lane * 2];
        acc.x += v0 * x0.x; acc.y += v0 * x0.y;
        acc.x += v1 * x1.x; acc.y += v1 * x1.y;
    }
    if (j < end) {
        int c = scol[j]; float v = sval[j];
        float2 x = *(const float2*)&dense[(long)c * 128 + lane * 2];
        acc.x += v * x.x; acc.y += v * x.y;
    }
    float a0 = acc.x > 0.f ? acc.x : 0.f;
    float a1 = acc.y > 0.f ? acc.y : 0.f;
    *(unsigned int*)(outb + (long)wid * 128 + lane * 2) =
        f2bf_rne(a0) | (f2bf_rne(a1) << 16);
}

// ---------------------------------------------------------------------------
// spmm2: out[row] = sum v * hw[col] ; one wave per row, D=64, fp32
// ---------------------------------------------------------------------------
__global__ __launch_bounds__(256) void spmm2(const int* __restrict__ rowptr,
                                             const int* __restrict__ scol,
                                             const float* __restrict__ sval,
                                             const float* __restrict__ dense,
                                             float* __restrict__ out) {
    const int wid = blockIdx.x * 4 + (threadIdx.x >> 6);
    if (wid >= N_NODES) return;
    const int lane = threadIdx.x & 63;
    const int start = rowptr[wid];
    const int end   = rowptr[wid + 1];

    float acc = 0.f;
    int j = start;
    for (; j + 1 < end; j += 2) {
        int c0 = scol[j];     float v0 = sval[j];
        int c1 = scol[j + 1]; float v1 = sval[j + 1];
        acc += v0 * dense[(long)c0 * 64 + lane] + v1 * dense[(long)c1 * 64 + lane];
    }
    if (j < end) acc += sval[j] * dense[(long)scol[j] * 64 + lane];
    out[(long)wid * 64 + lane] = acc;
}

// ---------------------------------------------------------------------------
extern "C" void kernel_launch(void* const* d_in, const int* in_sizes, int n_in,
                              void* d_out, int out_size, void* d_ws, size_t ws_size,
                              hipStream_t stream) {
    const float* feature = (const float*)d_in[0];
    const int*   erow    = (const int*)d_in[1];
    const int*   ecol    = (const int*)d_in[2];
    const float* evals   = (const float*)d_in[3];
    const float* W1      = (const float*)d_in[4];
    const float* W2      = (const float*)d_in[5];
    float* out = (float*)d_out;

    // workspace layout (~92 MB)
    float* support = (float*)d_ws;                              // 51.2 MB fp32
    float* hw      = support;                                   // alias (support dead after spmm1)
    unsigned short* hb = (unsigned short*)(support + (size_t)N_NODES * HID_DIM); // 25.6 MB bf16
    int*   cnt     = (int*)(hb + (size_t)N_NODES * HID_DIM);    // 400 KB
    int*   cursor  = cnt + N_NODES;                             // 400 KB
    int*   rowptr  = cursor + N_NODES;                          // 400 KB
    int*   scol    = rowptr + (N_NODES + 1);                    // 6.4 MB
    float* sval    = (float*)(scol + N_EDGES);                  // 6.4 MB
    int*   bsum    = (int*)(sval + N_EDGES);                    // 1.6 KB
    int*   boff    = bsum + SCAN_BLOCKS;                        // 1.6 KB
    unsigned short* W1t = (unsigned short*)(boff + SCAN_BLOCKS); // 128 KB bf16
    unsigned short* W2t = W1t + (size_t)HID_DIM * IN_DIM;       // 16 KB bf16

    // --- CSR build (counting sort by row) ---
    hipMemsetAsync(cnt, 0, (size_t)N_NODES * sizeof(int), stream);
    hist_rows<<<(N_EDGES + 255) / 256, 256, 0, stream>>>(erow, cnt);
    scan_pass1<<<SCAN_BLOCKS, 256, 0, stream>>>(cnt, bsum);
    scan_pass2<<<1, 512, 0, stream>>>(bsum, boff);
    scan_pass3<<<SCAN_BLOCKS, 256, 0, stream>>>(cnt, boff, rowptr, cursor);
    scatter_edges<<<(N_EDGES + 255) / 256, 256, 0, stream>>>(erow, ecol, evals,
                                                             cursor, scol, sval);

    // --- weight conversions (one-shot, tiny) ---
    wcvt<<<16, 256, 0, stream>>>(W1, W1t);
    wcvt2<<<1, 256, 0, stream>>>(W2, W2t);

    // layer 1: support = X @ W1  (bf16 MFMA)
    gemm1_mfma<<<(N_NODES + 63) / 64, 256, 0, stream>>>(feature, W1t, support);

    // h = relu(A @ support) -> bf16
    spmm1<<<(N_NODES + 3) / 4, 256, 0, stream>>>(rowptr, scol, sval, support, hb);

    // hw = h @ W2  (bf16 MFMA, W2 register-resident; writes over support)
    gemm2_mfma<<<(N_NODES + 127) / 128, 256, 0, stream>>>(hb, W2t, hw);

    // logits = A @ hw
    spmm2<<<(N_NODES + 3) / 4, 256, 0, stream>>>(rowptr, scol, sval, hw, out);
}

// Round 6
// 723.875 us; speedup vs baseline: 6.3512x; 1.0069x over previous
//
#include <hip/hip_runtime.h>

#define N_NODES 100000
#define N_EDGES 1600000
#define IN_DIM 512
#define HID_DIM 128
#define OUT_DIM 64

typedef __attribute__((ext_vector_type(8))) short bf16x8;
typedef __attribute__((ext_vector_type(4))) float f32x4;

__device__ __forceinline__ unsigned int f2bf_rne(float f) {
    union { float f; unsigned u; } v; v.f = f;
    unsigned r = v.u + 0x7fffu + ((v.u >> 16) & 1u);   // round-to-nearest-even
    return r >> 16;
}

// ---------------------------------------------------------------------------
// wcvt: W1t[128][512] bf16 = transpose(W1[512][128] fp32)   (one-shot, 16 blk)
// ---------------------------------------------------------------------------
__global__ __launch_bounds__(256) void wcvt(const float* __restrict__ W1,
                                            unsigned short* __restrict__ W1t) {
    __shared__ float T[64][65];
    const int bk = blockIdx.x >> 1;
    const int bn = blockIdx.x & 1;
    const int t = threadIdx.x;
#pragma unroll
    for (int i = 0; i < 4; i++) {
        int fi = t + i * 256;
        int kk = fi >> 4;
        int f  = fi & 15;
        float4 v = *(const float4*)&W1[(long)(bk * 64 + kk) * HID_DIM + bn * 64 + f * 4];
        T[kk][f * 4 + 0] = v.x; T[kk][f * 4 + 1] = v.y;
        T[kk][f * 4 + 2] = v.z; T[kk][f * 4 + 3] = v.w;
    }
    __syncthreads();
#pragma unroll
    for (int i = 0; i < 8; i++) {
        int di = t + i * 256;
        int n  = di >> 5;
        int dw = di & 31;
        unsigned lo = f2bf_rne(T[dw * 2 + 0][n]);
        unsigned hi = f2bf_rne(T[dw * 2 + 1][n]);
        unsigned short* dst = W1t + (long)(bn * 64 + n) * IN_DIM + bk * 64 + dw * 2;
        *(unsigned int*)dst = lo | (hi << 16);
    }
}

// ---------------------------------------------------------------------------
// wcvt2: W2t[64][128] bf16 = transpose(W2[128][64] fp32)   (one-shot, 1 blk)
// ---------------------------------------------------------------------------
__global__ __launch_bounds__(256) void wcvt2(const float* __restrict__ W2,
                                             unsigned short* __restrict__ W2t) {
    __shared__ float T[128][65];
    const int t = threadIdx.x;
#pragma unroll
    for (int i = 0; i < 8; i++) {
        int fi = t + i * 256;
        int k = fi >> 4;
        int f = fi & 15;
        float4 v = *(const float4*)&W2[(long)k * OUT_DIM + f * 4];
        T[k][f * 4 + 0] = v.x; T[k][f * 4 + 1] = v.y;
        T[k][f * 4 + 2] = v.z; T[k][f * 4 + 3] = v.w;
    }
    __syncthreads();
#pragma unroll
    for (int i = 0; i < 16; i++) {
        int di = t + i * 256;
        int n  = di >> 6;
        int dw = di & 63;
        unsigned lo = f2bf_rne(T[dw * 2 + 0][n]);
        unsigned hi = f2bf_rne(T[dw * 2 + 1][n]);
        *(unsigned int*)(W2t + (long)n * HID_DIM + dw * 2) = lo | (hi << 16);
    }
}

// ---------------------------------------------------------------------------
// gemm1_mfma: support_bf16[100000,128] = X[100000,512] @ W1  (bf16 MFMA)
// ---------------------------------------------------------------------------
__global__ __launch_bounds__(256) void gemm1_mfma(const float* __restrict__ X,
                                                  const unsigned short* __restrict__ W1t,
                                                  unsigned short* __restrict__ outb) {
    __shared__ unsigned short As[64][40];
    const int tid  = threadIdx.x;
    const int lane = tid & 63;
    const int w    = tid >> 6;
    const int m    = lane & 15;
    const int hi   = lane >> 4;
    const int rowBase = blockIdx.x * 64;

    f32x4 acc[4][2] = {};

    const int sr = tid >> 2;
    const int sk = (tid & 3) * 8;
    int gr = rowBase + sr;
    if (gr >= N_NODES) gr = N_NODES - 1;
    const float* xp = X + (long)gr * IN_DIM;

    const unsigned short* b0p = W1t + (long)(w * 32 + m) * IN_DIM + hi * 8;
    const unsigned short* b1p = W1t + (long)(w * 32 + 16 + m) * IN_DIM + hi * 8;

    for (int k0 = 0; k0 < IN_DIM; k0 += 32) {
        float4 xa = *(const float4*)(xp + k0 + sk);
        float4 xb = *(const float4*)(xp + k0 + sk + 4);
        uint4 pk;
        pk.x = f2bf_rne(xa.x) | (f2bf_rne(xa.y) << 16);
        pk.y = f2bf_rne(xa.z) | (f2bf_rne(xa.w) << 16);
        pk.z = f2bf_rne(xb.x) | (f2bf_rne(xb.y) << 16);
        pk.w = f2bf_rne(xb.z) | (f2bf_rne(xb.w) << 16);
        *(uint4*)&As[sr][sk] = pk;
        __syncthreads();

        bf16x8 bf0 = *(const bf16x8*)(b0p + k0);
        bf16x8 bf1 = *(const bf16x8*)(b1p + k0);
#pragma unroll
        for (int t = 0; t < 4; t++) {
            bf16x8 af = *(const bf16x8*)&As[t * 16 + m][hi * 8];
            acc[t][0] = __builtin_amdgcn_mfma_f32_16x16x32_bf16(af, bf0, acc[t][0], 0, 0, 0);
            acc[t][1] = __builtin_amdgcn_mfma_f32_16x16x32_bf16(af, bf1, acc[t][1], 0, 0, 0);
        }
        __syncthreads();
    }

    // D layout: col = lane&15, row = (lane>>4)*4 + reg ; store bf16
#pragma unroll
    for (int t = 0; t < 4; t++) {
#pragma unroll
        for (int r = 0; r < 4; r++) {
            int row = rowBase + t * 16 + hi * 4 + r;
            if (row < N_NODES) {
                outb[(long)row * HID_DIM + w * 32 + m] =
                    (unsigned short)f2bf_rne(acc[t][0][r]);
                outb[(long)row * HID_DIM + w * 32 + 16 + m] =
                    (unsigned short)f2bf_rne(acc[t][1][r]);
            }
        }
    }
}

// ---------------------------------------------------------------------------
// gemm2_mfma: hw[100000,64] fp32 = h_bf16[100000,128] @ W2  (W2 in registers)
// ---------------------------------------------------------------------------
__global__ __launch_bounds__(256) void gemm2_mfma(const unsigned short* __restrict__ hb,
                                                  const unsigned short* __restrict__ W2t,
                                                  float* __restrict__ hw) {
    const int tid  = threadIdx.x;
    const int lane = tid & 63;
    const int w    = tid >> 6;
    const int m    = lane & 15;
    const int hi   = lane >> 4;
    const long rowBase = (long)blockIdx.x * 128 + w * 32;

    bf16x8 bfrag[4][4];
#pragma unroll
    for (int nt = 0; nt < 4; nt++) {
        const unsigned short* bp = W2t + (long)(nt * 16 + m) * HID_DIM + hi * 8;
#pragma unroll
        for (int ks = 0; ks < 4; ks++)
            bfrag[ks][nt] = *(const bf16x8*)(bp + ks * 32);
    }

    f32x4 acc[2][4] = {};
#pragma unroll
    for (int mt = 0; mt < 2; mt++) {
        long r = rowBase + mt * 16 + m;
        if (r >= N_NODES) r = N_NODES - 1;
        const unsigned short* ap = hb + r * HID_DIM + hi * 8;
#pragma unroll
        for (int ks = 0; ks < 4; ks++) {
            bf16x8 af = *(const bf16x8*)(ap + ks * 32);
#pragma unroll
            for (int nt = 0; nt < 4; nt++)
                acc[mt][nt] = __builtin_amdgcn_mfma_f32_16x16x32_bf16(
                    af, bfrag[ks][nt], acc[mt][nt], 0, 0, 0);
        }
    }

#pragma unroll
    for (int mt = 0; mt < 2; mt++)
#pragma unroll
        for (int nt = 0; nt < 4; nt++)
#pragma unroll
            for (int r = 0; r < 4; r++) {
                long row = rowBase + mt * 16 + hi * 4 + r;
                if (row < N_NODES)
                    hw[row * OUT_DIM + nt * 16 + m] = acc[mt][nt][r];
            }
}

// ---------------------------------------------------------------------------
// CSR build: histogram -> 3-phase parallel exclusive scan -> scatter (packed)
// ---------------------------------------------------------------------------
__global__ __launch_bounds__(256) void hist_rows(const int* __restrict__ rows,
                                                 int* __restrict__ cnt) {
    int e = blockIdx.x * 256 + threadIdx.x;
    if (e < N_EDGES) atomicAdd(&cnt[rows[e]], 1);
}

#define SCAN_BLOCKS ((N_NODES + 255) / 256)   // 391

__global__ __launch_bounds__(256) void scan_pass1(int* __restrict__ cnt,
                                                  int* __restrict__ bsum) {
    __shared__ int s[256];
    const int t = threadIdx.x;
    const int i = blockIdx.x * 256 + t;
    int v = (i < N_NODES) ? cnt[i] : 0;
    s[t] = v;
    __syncthreads();
    for (int off = 1; off < 256; off <<= 1) {
        int u = (t >= off) ? s[t - off] : 0;
        __syncthreads();
        s[t] += u;
        __syncthreads();
    }
    if (i < N_NODES) cnt[i] = s[t] - v;
    if (t == 255) bsum[blockIdx.x] = s[255];
}

__global__ __launch_bounds__(512) void scan_pass2(int* __restrict__ bsum,
                                                  int* __restrict__ boff) {
    __shared__ int s[512];
    const int t = threadIdx.x;
    int v = (t < SCAN_BLOCKS) ? bsum[t] : 0;
    s[t] = v;
    __syncthreads();
    for (int off = 1; off < 512; off <<= 1) {
        int u = (t >= off) ? s[t - off] : 0;
        __syncthreads();
        s[t] += u;
        __syncthreads();
    }
    if (t < SCAN_BLOCKS) boff[t] = s[t] - v;
}

__global__ __launch_bounds__(256) void scan_pass3(const int* __restrict__ cnt,
                                                  const int* __restrict__ boff,
                                                  int* __restrict__ rowptr,
                                                  int* __restrict__ cursor) {
    const int i = blockIdx.x * 256 + threadIdx.x;
    if (i < N_NODES) {
        int r = cnt[i] + boff[blockIdx.x];
        rowptr[i] = r;
        cursor[i] = r;
    }
    if (i == 0) rowptr[N_NODES] = N_EDGES;
}

__global__ __launch_bounds__(256) void scatter_edges(const int* __restrict__ rows,
                                                     const int* __restrict__ cols,
                                                     const float* __restrict__ vals,
                                                     int* __restrict__ cursor,
                                                     int2* __restrict__ sedge) {
    int e = blockIdx.x * 256 + threadIdx.x;
    if (e < N_EDGES) {
        int p = atomicAdd(&cursor[rows[e]], 1);
        sedge[p] = make_int2(cols[e], __float_as_int(vals[e]));
    }
}

// ---------------------------------------------------------------------------
// spmm1: h_bf16[row] = relu(sum v * support_bf16[col]) ; wave/row, D=128
// Gather: one dword (2 bf16) per lane per edge = 256 B/edge.
// ---------------------------------------------------------------------------
__global__ __launch_bounds__(256) void spmm1(const int* __restrict__ rowptr,
                                             const int2* __restrict__ sedge,
                                             const unsigned short* __restrict__ supb,
                                             unsigned short* __restrict__ outb) {
    const int wid = blockIdx.x * 4 + (threadIdx.x >> 6);
    if (wid >= N_NODES) return;
    const int lane = threadIdx.x & 63;
    const int start = rowptr[wid];
    const int end   = rowptr[wid + 1];

    float accx = 0.f, accy = 0.f;
    int j = start;
    for (; j + 1 < end; j += 2) {
        int2 e0 = sedge[j];
        int2 e1 = sedge[j + 1];
        float v0 = __int_as_float(e0.y);
        float v1 = __int_as_float(e1.y);
        unsigned u0 = *(const unsigned*)(supb + (long)e0.x * 128 + lane * 2);
        unsigned u1 = *(const unsigned*)(supb + (long)e1.x * 128 + lane * 2);
        float x0l = __uint_as_float(u0 << 16);
        float x0h = __uint_as_float(u0 & 0xffff0000u);
        float x1l = __uint_as_float(u1 << 16);
        float x1h = __uint_as_float(u1 & 0xffff0000u);
        accx += v0 * x0l + v1 * x1l;
        accy += v0 * x0h + v1 * x1h;
    }
    if (j < end) {
        int2 e = sedge[j];
        float v = __int_as_float(e.y);
        unsigned u = *(const unsigned*)(supb + (long)e.x * 128 + lane * 2);
        accx += v * __uint_as_float(u << 16);
        accy += v * __uint_as_float(u & 0xffff0000u);
    }
    accx = accx > 0.f ? accx : 0.f;
    accy = accy > 0.f ? accy : 0.f;
    *(unsigned int*)(outb + (long)wid * 128 + lane * 2) =
        f2bf_rne(accx) | (f2bf_rne(accy) << 16);
}

// ---------------------------------------------------------------------------
// spmm2: out[row] = sum v * hw[col] ; wave/row, D=64, fp32 (logits path)
// ---------------------------------------------------------------------------
__global__ __launch_bounds__(256) void spmm2(const int* __restrict__ rowptr,
                                             const int2* __restrict__ sedge,
                                             const float* __restrict__ dense,
                                             float* __restrict__ out) {
    const int wid = blockIdx.x * 4 + (threadIdx.x >> 6);
    if (wid >= N_NODES) return;
    const int lane = threadIdx.x & 63;
    const int start = rowptr[wid];
    const int end   = rowptr[wid + 1];

    float acc = 0.f;
    int j = start;
    for (; j + 1 < end; j += 2) {
        int2 e0 = sedge[j];
        int2 e1 = sedge[j + 1];
        acc += __int_as_float(e0.y) * dense[(long)e0.x * 64 + lane]
             + __int_as_float(e1.y) * dense[(long)e1.x * 64 + lane];
    }
    if (j < end) {
        int2 e = sedge[j];
        acc += __int_as_float(e.y) * dense[(long)e.x * 64 + lane];
    }
    out[(long)wid * 64 + lane] = acc;
}

// ---------------------------------------------------------------------------
extern "C" void kernel_launch(void* const* d_in, const int* in_sizes, int n_in,
                              void* d_out, int out_size, void* d_ws, size_t ws_size,
                              hipStream_t stream) {
    const float* feature = (const float*)d_in[0];
    const int*   erow    = (const int*)d_in[1];
    const int*   ecol    = (const int*)d_in[2];
    const float* evals   = (const float*)d_in[3];
    const float* W1      = (const float*)d_in[4];
    const float* W2      = (const float*)d_in[5];
    float* out = (float*)d_out;

    // workspace layout (~91 MB)
    unsigned short* supb = (unsigned short*)d_ws;                 // 25.6 MB bf16
    unsigned short* hb   = supb + (size_t)N_NODES * HID_DIM;      // 25.6 MB bf16
    float* hw      = (float*)(hb + (size_t)N_NODES * HID_DIM);    // 25.6 MB fp32
    int*   cnt     = (int*)(hw + (size_t)N_NODES * OUT_DIM);      // 400 KB
    int*   cursor  = cnt + N_NODES;                               // 400 KB
    int*   rowptr  = cursor + N_NODES;                            // 400 KB
    int2*  sedge   = (int2*)(rowptr + (N_NODES + 1));             // 12.8 MB
    int*   bsum    = (int*)(sedge + N_EDGES);                     // 1.6 KB
    int*   boff    = bsum + SCAN_BLOCKS;                          // 1.6 KB
    unsigned short* W1t = (unsigned short*)(boff + SCAN_BLOCKS);  // 128 KB bf16
    unsigned short* W2t = W1t + (size_t)HID_DIM * IN_DIM;         // 16 KB bf16

    // --- CSR build (counting sort by row) ---
    hipMemsetAsync(cnt, 0, (size_t)N_NODES * sizeof(int), stream);
    hist_rows<<<(N_EDGES + 255) / 256, 256, 0, stream>>>(erow, cnt);
    scan_pass1<<<SCAN_BLOCKS, 256, 0, stream>>>(cnt, bsum);
    scan_pass2<<<1, 512, 0, stream>>>(bsum, boff);
    scan_pass3<<<SCAN_BLOCKS, 256, 0, stream>>>(cnt, boff, rowptr, cursor);
    scatter_edges<<<(N_EDGES + 255) / 256, 256, 0, stream>>>(erow, ecol, evals,
                                                             cursor, sedge);

    // --- weight conversions (one-shot, tiny) ---
    wcvt<<<16, 256, 0, stream>>>(W1, W1t);
    wcvt2<<<1, 256, 0, stream>>>(W2, W2t);

    // layer 1: support = X @ W1  -> bf16
    gemm1_mfma<<<(N_NODES + 63) / 64, 256, 0, stream>>>(feature, W1t, supb);

    // h = relu(A @ support) -> bf16
    spmm1<<<(N_NODES + 3) / 4, 256, 0, stream>>>(rowptr, sedge, supb, hb);

    // hw = h @ W2 -> fp32
    gemm2_mfma<<<(N_NODES + 127) / 128, 256, 0, stream>>>(hb, W2t, hw);

    // logits = A @ hw
    spmm2<<<(N_NODES + 3) / 4, 256, 0, stream>>>(rowptr, sedge, hw, out);
}